// Round 15
// baseline (450.234 us; speedup 1.0000x reference)
//
#include <hip/hip_runtime.h>
#include <cstdint>
#include <cstddef>

// Problem constants (fixed by the reference).
constexpr int kN = 50000;      // nodes  (< 65536 -> src ids fit in uint16)
constexpr int kE = 800000;     // edges
constexpr int kG = 512;        // graphs
constexpr float kNegSlope = 0.2f;

typedef float f4v __attribute__((ext_vector_type(4)));
typedef _Float16 h2v __attribute__((ext_vector_type(2)));
typedef _Float16 h4v __attribute__((ext_vector_type(4)));
typedef _Float16 h8v __attribute__((ext_vector_type(8)));

#if defined(__has_builtin)
#if __has_builtin(__builtin_amdgcn_fdot2)
#define HAS_FDOT2 1
#endif
#endif

__device__ inline float dot2f(h2v a, h2v b, float c) {
#ifdef HAS_FDOT2
  return __builtin_amdgcn_fdot2(a, b, c, false);
#else
  return c + (float)a.x * (float)b.x + (float)a.y * (float)b.y;
#endif
}

// ---------------------------------------------------------------------------
// CSR build: histogram of dst (records each edge's within-node slot) ->
// block-scan -> fused top-scan+add -> scatter (no atomics in scatter).
// ---------------------------------------------------------------------------
__global__ void k_hist(const int* __restrict__ dst, int* __restrict__ counts,
                       int* __restrict__ pos, int n) {
  int i = blockIdx.x * blockDim.x + threadIdx.x;
  if (i < n) pos[i] = atomicAdd(&counts[dst[i]], 1);
}

__global__ __launch_bounds__(256) void k_scan_blk(const int* __restrict__ counts,
                                                  int* __restrict__ excl,
                                                  int* __restrict__ bsums, int n) {
  __shared__ int sh[256];
  int tid = threadIdx.x;
  int i = blockIdx.x * 256 + tid;
  int c = (i < n) ? counts[i] : 0;
  sh[tid] = c;
  __syncthreads();
  for (int off = 1; off < 256; off <<= 1) {
    int t = (tid >= off) ? sh[tid - off] : 0;
    __syncthreads();
    sh[tid] += t;
    __syncthreads();
  }
  if (i < n) excl[i] = sh[tid] - c;
  if (tid == 255) bsums[blockIdx.x] = sh[255];
}

// Fused top-scan + add: every block scans the (<=256) block sums in LDS,
// picks its own offset, and emits final row_ptr (incl. row_ptr[n] = total).
__global__ __launch_bounds__(256) void k_scan_add(const int* __restrict__ excl,
                                                  const int* __restrict__ bsums,
                                                  int* __restrict__ row_ptr,
                                                  int n, int nb) {
  __shared__ int sh[256];
  int tid = threadIdx.x;
  int c = (tid < nb) ? bsums[tid] : 0;
  sh[tid] = c;
  __syncthreads();
  for (int off = 1; off < 256; off <<= 1) {
    int t = (tid >= off) ? sh[tid - off] : 0;
    __syncthreads();
    sh[tid] += t;
    __syncthreads();
  }
  int top = (blockIdx.x > 0) ? sh[blockIdx.x - 1] : 0;
  int total = sh[nb - 1];
  __syncthreads();
  int i = blockIdx.x * 256 + tid;
  if (i < n) row_ptr[i] = excl[i] + top;
  if (i == n) row_ptr[n] = total;
}

__global__ void k_scatter(const int* __restrict__ src, const int* __restrict__ dst,
                          const float* __restrict__ eattr,
                          const int* __restrict__ row_ptr, const int* __restrict__ pos,
                          uint16_t* __restrict__ csr_src, _Float16* __restrict__ csr_ea,
                          int n) {
  int i = blockIdx.x * blockDim.x + threadIdx.x;
  if (i >= n) return;
  int p = row_ptr[dst[i]] + pos[i];
  csr_src[p] = (uint16_t)src[i];
  const float4* s4 = (const float4*)eattr + (size_t)i * 2;
  float4 a = s4[0];
  float4 b = s4[1];
  h8v hv;
  hv[0] = (_Float16)a.x; hv[1] = (_Float16)a.y; hv[2] = (_Float16)a.z; hv[3] = (_Float16)a.w;
  hv[4] = (_Float16)b.x; hv[5] = (_Float16)b.y; hv[6] = (_Float16)b.z; hv[7] = (_Float16)b.w;
  *(h8v*)(csr_ea + (size_t)p * 8) = hv;
}

// ---------------------------------------------------------------------------
// Fused prep: ALSO zeroes counts (replaces the memset launch; prep runs
// before k_hist).  x -> fp16 padded K=32; weight pairs -> fp16 transposed
// Wt buffers; We -> fp16 transposed Wet[ch][k] tables.
// ---------------------------------------------------------------------------
__global__ __launch_bounds__(256) void k_prep(
    const float* __restrict__ x,
    const float* __restrict__ W1s, const float* __restrict__ W1d,
    const float* __restrict__ W2s, const float* __restrict__ W2d,
    const float* __restrict__ W3s, const float* __restrict__ W3d,
    const float* __restrict__ W1e, const float* __restrict__ W2e,
    const float* __restrict__ W3e,
    int* __restrict__ counts,
    _Float16* __restrict__ xf, _Float16* __restrict__ Wt1,
    _Float16* __restrict__ Wt2, _Float16* __restrict__ Wt3,
    _Float16* __restrict__ We1t, _Float16* __restrict__ We2t,
    _Float16* __restrict__ We3t, int n) {
  int i = blockIdx.x * 256 + threadIdx.x;
  if (i < n) {
    counts[i] = 0;
  }
  i -= n;
  if (i < 0) return;
  int r0 = n * 32;
  if (i < r0) {
    int node = i >> 5, col = i & 31;
    xf[i] = (col < 16) ? (_Float16)x[node * 16 + col] : (_Float16)0.f;
    return;
  }
  i -= r0;
  if (i < 256 * 32) {  // Wt1: 256 cols x K=32, IND=16, OUTD=128
    int c = i >> 5, k = i & 31;
    const float* W = (c < 128) ? W1s : W1d;
    Wt1[i] = (k < 16) ? (_Float16)W[k * 128 + (c & 127)] : (_Float16)0.f;
    return;
  }
  i -= 256 * 32;
  if (i < 256 * 128) {  // Wt2: 256 x 128, IND=128, OUTD=128
    int c = i >> 7, k = i & 127;
    const float* W = (c < 128) ? W2s : W2d;
    Wt2[i] = (_Float16)W[k * 128 + (c & 127)];
    return;
  }
  i -= 256 * 128;
  if (i < 64 * 128) {  // Wt3: 64 x 128, IND=128, OUTD=32
    int c = i >> 7, k = i & 127;
    const float* W = (c < 32) ? W3s : W3d;
    int cc = (c < 32) ? c : c - 32;
    Wt3[i] = (_Float16)W[k * 32 + cc];
    return;
  }
  i -= 64 * 128;
  if (i < 128 * 8) {  // We1t[ch][k] = W1e[k][ch]
    We1t[i] = (_Float16)W1e[(i & 7) * 128 + (i >> 3)];
    return;
  }
  i -= 128 * 8;
  if (i < 128 * 8) {  // We2t
    We2t[i] = (_Float16)W2e[(i & 7) * 128 + (i >> 3)];
    return;
  }
  i -= 128 * 8;
  if (i < 32 * 8) {   // We3t
    We3t[i] = (_Float16)W3e[(i & 7) * 32 + (i >> 3)];
  }
}

// ---------------------------------------------------------------------------
// MFMA node transform: [xs | xd] = h @ [Ws | Wd] + [bs | bd].  Both outputs
// fp16 (xd quantization adds ~2e-4 to final error; margin 4x).
// ---------------------------------------------------------------------------
template <int KT, int NC2>
__global__ __launch_bounds__(256) void k_tmfma(
    const _Float16* __restrict__ hf, const _Float16* __restrict__ Wt,
    const float* __restrict__ bs, const float* __restrict__ bd,
    _Float16* __restrict__ xs_h, _Float16* __restrict__ xd_h, int n_nodes) {
  constexpr int K = KT * 32;
  constexpr int NCS = NC2 / 2;
  constexpr int D = NCS * 16;
  int lane = threadIdx.x & 63;
  int wid = threadIdx.x >> 6;
  int m = lane & 15;
  int quad = lane >> 4;
  int base = (blockIdx.x * 4 + wid) * 16;
  if (base >= n_nodes) return;
  int arow = min(base + m, n_nodes - 1);

  h8v a[KT];
#pragma unroll
  for (int t = 0; t < KT; ++t)
    a[t] = *(const h8v*)(hf + (size_t)arow * K + t * 32 + quad * 8);

  bool full = (base + 16 <= n_nodes);
#pragma unroll
  for (int c = 0; c < NC2; ++c) {
    f4v acc = {0.f, 0.f, 0.f, 0.f};
#pragma unroll
    for (int t = 0; t < KT; ++t) {
      h8v b = *(const h8v*)(Wt + (size_t)(c * 16 + m) * K + t * 32 + quad * 8);
      acc = __builtin_amdgcn_mfma_f32_16x16x32_f16(a[t], b, acc, 0, 0, 0);
    }
    float bv = (c < NCS) ? bs[c * 16 + m] : bd[(c - NCS) * 16 + m];
#pragma unroll
    for (int r = 0; r < 4; ++r) {
      int node = base + quad * 4 + r;
      if (full || node < n_nodes) {
        if (c < NCS)
          xs_h[(size_t)node * D + c * 16 + m] = (_Float16)(acc[r] + bv);
        else
          xd_h[(size_t)node * D + (c - NCS) * 16 + m] = (_Float16)(acc[r] + bv);
      }
    }
  }
}

// ---------------------------------------------------------------------------
// Fused GATv2, D=128 (H=4, C=32): NON-persistent, ONE WAVE PER BLOCK
// (64 threads — waves retire individually, occupancy 63% measured R14).
// TWO edge slots (32 lanes/slot, 4 ch/lane — measured knee).  Software
// pipeline DEPTH 4 with WAVE-UNIFORM prefetch guard (i+8 < cnt): R12's
// unguarded depth-4 wasted ~25% gathers at deg 16 and regressed; the guard
// makes deg-16 exactly 4 initial + 4 guarded loads, zero waste, 8 in
// flight (vs 2) — attacks the Little's-law latency-MLP limit measured at
// 1.69 TB/s.  No-max softmax (scores bounded ~|6| << 88).  Chunked: 64 src
// ids preloaded coalesced (lanes>=cnt hold 0 -> valid address, masked by
// p=0), ea staged in wave-private LDS, dot2 chain seeded with xs+xd.
// Bounds: consume e = i+6+slot <= 63; guarded prefetch idx <= 63.
// ---------------------------------------------------------------------------
template <bool DO_ELU>
__global__ __launch_bounds__(64) void k_gat128(
    const int* __restrict__ row_ptr, const uint16_t* __restrict__ csr_src,
    const _Float16* __restrict__ csr_ea,
    const _Float16* __restrict__ xs_h, const _Float16* __restrict__ xd_h,
    const float* __restrict__ att, const float* __restrict__ bias,
    const _Float16* __restrict__ Wet, _Float16* __restrict__ hout, int n_nodes) {
  __shared__ _Float16 sea[64 * 8];
  int lane = threadIdx.x & 63;
  int node = blockIdx.x;
  if (node >= n_nodes) return;
  int slot = lane >> 5;   // 0 / 1
  int sl = lane & 31;
  int ch0 = sl * 4;       // this lane's 4 channels; head = sl>>3

  float4 at4 = *(const float4*)(att + ch0);
  float atl[4] = {at4.x, at4.y, at4.z, at4.w};
  h2v we[4][4];
#pragma unroll
  for (int c = 0; c < 4; ++c) {
    h8v wv = *(const h8v*)(Wet + (size_t)(ch0 + c) * 8);
#pragma unroll
    for (int t = 0; t < 4; ++t) {
      h2v w;
      w[0] = wv[2 * t];
      w[1] = wv[2 * t + 1];
      we[c][t] = w;
    }
  }
  float4 bv4 = *(const float4*)(bias + ch0);
  float bl[4] = {bv4.x, bv4.y, bv4.z, bv4.w};

  h4v xdh = *(const h4v*)(xd_h + (size_t)node * 128 + ch0);
  float xdl[4];
#pragma unroll
  for (int c = 0; c < 4; ++c) xdl[c] = (float)xdh[c];

  const char* xsb = (const char*)xs_h;
  uint32_t chb = (uint32_t)sl * 8u;  // byte offset of this lane's 4 fp16 ch

  float acc[4] = {0.f, 0.f, 0.f, 0.f};
  float l_run = 0.f;
  int beg = row_ptr[node], end = row_ptr[node + 1];

  for (int cbeg = beg; cbeg < end; cbeg += 64) {
    int cnt = min(end - cbeg, 64);
    int sv = (lane < cnt) ? (int)__builtin_nontemporal_load(csr_src + cbeg + lane) : 0;
    if (lane < cnt) {
      h8v t = __builtin_nontemporal_load((const h8v*)(csr_ea + (size_t)(cbeg + lane) * 8));
      *(h8v*)&sea[lane * 8] = t;
    }

    auto addr = [&](int i) -> uint32_t {
      int s = __shfl(sv, i + slot, 64);  // idx <= 63 everywhere it's used
      return (uint32_t)s * 256u + chb;
    };
    auto consume = [&](int i, h4v xh) {
      int e = i + slot;                  // <= 63 by construction
      const h2v* pe = (const h2v*)&sea[e * 8];
      h2v a0 = pe[0], a1 = pe[1], a2 = pe[2], a3 = pe[3];
      float xf[4];
#pragma unroll
      for (int c = 0; c < 4; ++c) xf[c] = (float)xh[c];
      float sc = 0.f;
#pragma unroll
      for (int c = 0; c < 4; ++c) {
        float z = dot2f(a3, we[c][3],
                  dot2f(a2, we[c][2],
                  dot2f(a1, we[c][1],
                  dot2f(a0, we[c][0], xf[c] + xdl[c]))));
        z = fmaxf(z, kNegSlope * z);
        sc = fmaf(z, atl[c], sc);
      }
      // head score: reduce over the 8 lanes covering this head's 32 ch
      sc += __shfl_xor(sc, 1, 64);
      sc += __shfl_xor(sc, 2, 64);
      sc += __shfl_xor(sc, 4, 64);
      float p = (e < cnt) ? __expf(sc) : 0.f;
      l_run += p;
#pragma unroll
      for (int c = 0; c < 4; ++c) acc[c] += p * xf[c];
    };

    uint32_t o0 = addr(0), o1 = addr(2), o2 = addr(4), o3 = addr(6);
    h4v x0 = *(const h4v*)(xsb + o0);
    h4v x1 = *(const h4v*)(xsb + o1);
    h4v x2 = *(const h4v*)(xsb + o2);
    h4v x3 = *(const h4v*)(xsb + o3);
    for (int i = 0; i < cnt; i += 8) {
      bool pf = (i + 8 < cnt);           // wave-uniform: zero wasted gathers
      h4v p0, p1, p2, p3;
      if (pf) {
        uint32_t n0 = addr(i + 8), n1 = addr(i + 10);
        uint32_t n2 = addr(i + 12), n3 = addr(i + 14);
        p0 = *(const h4v*)(xsb + n0);
        p1 = *(const h4v*)(xsb + n1);
        p2 = *(const h4v*)(xsb + n2);
        p3 = *(const h4v*)(xsb + n3);
      }
      consume(i, x0);
      consume(i + 2, x1);
      consume(i + 4, x2);
      consume(i + 6, x3);
      if (pf) { x0 = p0; x1 = p1; x2 = p2; x3 = p3; }
    }
  }

  // combine the two slots
  l_run += __shfl_xor(l_run, 32, 64);
#pragma unroll
  for (int c = 0; c < 4; ++c) acc[c] += __shfl_xor(acc[c], 32, 64);

  if (slot == 0) {
    float inv = (l_run > 0.f) ? (1.f / l_run) : 0.f;
    h4v ov;
#pragma unroll
    for (int c = 0; c < 4; ++c) {
      float o = acc[c] * inv + bl[c];
      if (DO_ELU) o = (o > 0.f) ? o : (__expf(o) - 1.f);
      ov[c] = (_Float16)o;
    }
    __builtin_nontemporal_store(ov, (h4v*)(hout + (size_t)node * 128 + ch0));
  }
}

// ---------------------------------------------------------------------------
// Fused GATv2, D=32 (H=1, C=32): NON-persistent, one wave per block,
// EIGHT edge slots (8 lanes/slot, 4 ch/lane), pipeline depth 2 with
// wave-uniform prefetch guard (kills the ~2 wasted gathers/node at deg 16;
// initial window of 16 edges already covers the typical node).
// Chunk = 32 edges.
// ---------------------------------------------------------------------------
template <bool DO_ELU>
__global__ __launch_bounds__(64) void k_gat32(
    const int* __restrict__ row_ptr, const uint16_t* __restrict__ csr_src,
    const _Float16* __restrict__ csr_ea,
    const _Float16* __restrict__ xs_h, const _Float16* __restrict__ xd_h,
    const float* __restrict__ att, const float* __restrict__ bias,
    const _Float16* __restrict__ Wet, _Float16* __restrict__ hout, int n_nodes) {
  __shared__ _Float16 sea[32 * 8];
  int lane = threadIdx.x & 63;
  int node = blockIdx.x;
  if (node >= n_nodes) return;
  int slot = lane >> 3;   // 0..7
  int sl = lane & 7;
  int ch0 = sl * 4;

  float4 at4 = *(const float4*)(att + ch0);
  float atl[4] = {at4.x, at4.y, at4.z, at4.w};
  h2v we[4][4];
#pragma unroll
  for (int c = 0; c < 4; ++c) {
    h8v wv = *(const h8v*)(Wet + (size_t)(ch0 + c) * 8);
#pragma unroll
    for (int t = 0; t < 4; ++t) {
      h2v w;
      w[0] = wv[2 * t];
      w[1] = wv[2 * t + 1];
      we[c][t] = w;
    }
  }
  float4 bv4 = *(const float4*)(bias + ch0);
  float bl[4] = {bv4.x, bv4.y, bv4.z, bv4.w};

  h4v xdh = *(const h4v*)(xd_h + (size_t)node * 32 + ch0);
  float xdl[4];
#pragma unroll
  for (int c = 0; c < 4; ++c) xdl[c] = (float)xdh[c];

  const char* xsb = (const char*)xs_h;
  uint32_t chb = (uint32_t)sl * 8u;

  float acc[4] = {0.f, 0.f, 0.f, 0.f};
  float l_run = 0.f;
  int beg = row_ptr[node], end = row_ptr[node + 1];

  for (int cbeg = beg; cbeg < end; cbeg += 32) {
    int cnt = min(end - cbeg, 32);
    int sv = (lane < cnt) ? (int)__builtin_nontemporal_load(csr_src + cbeg + lane) : 0;
    if (lane < cnt) {
      h8v t = __builtin_nontemporal_load((const h8v*)(csr_ea + (size_t)(cbeg + lane) * 8));
      *(h8v*)&sea[lane * 8] = t;
    }

    auto addr = [&](int i) -> uint32_t {
      int idx = (i + slot) & 31;         // wrap within this chunk's 32 ids
      int s = __shfl(sv, idx, 64);
      return (uint32_t)s * 64u + chb;
    };
    auto consume = [&](int i, h4v xh) {
      int e = i + slot;                  // <= 31 by construction
      const h2v* pe = (const h2v*)&sea[e * 8];
      h2v a0 = pe[0], a1 = pe[1], a2 = pe[2], a3 = pe[3];
      float xf[4];
#pragma unroll
      for (int c = 0; c < 4; ++c) xf[c] = (float)xh[c];
      float sc = 0.f;
#pragma unroll
      for (int c = 0; c < 4; ++c) {
        float z = dot2f(a3, we[c][3],
                  dot2f(a2, we[c][2],
                  dot2f(a1, we[c][1],
                  dot2f(a0, we[c][0], xf[c] + xdl[c]))));
        z = fmaxf(z, kNegSlope * z);
        sc = fmaf(z, atl[c], sc);
      }
      // head = 32 ch = 8 lanes (this slot)
      sc += __shfl_xor(sc, 1, 64);
      sc += __shfl_xor(sc, 2, 64);
      sc += __shfl_xor(sc, 4, 64);
      float p = (e < cnt) ? __expf(sc) : 0.f;
      l_run += p;
#pragma unroll
      for (int c = 0; c < 4; ++c) acc[c] += p * xf[c];
    };

    uint32_t oa = addr(0), ob = addr(8);
    h4v xa = *(const h4v*)(xsb + oa);
    h4v xb = *(const h4v*)(xsb + ob);
    for (int i = 0; i < cnt; i += 16) {
      bool pf = (i + 16 < cnt);          // wave-uniform guard
      h4v pa, pb;
      if (pf) {
        uint32_t na = addr(i + 16), nb = addr(i + 24);
        pa = *(const h4v*)(xsb + na);
        pb = *(const h4v*)(xsb + nb);
      }
      consume(i, xa);
      consume(i + 8, xb);
      if (pf) { xa = pa; xb = pb; }
    }
  }

  // combine the 8 slots (lanes with equal sl)
#pragma unroll
  for (int off = 8; off < 64; off <<= 1) {
    l_run += __shfl_xor(l_run, off, 64);
#pragma unroll
    for (int c = 0; c < 4; ++c) acc[c] += __shfl_xor(acc[c], off, 64);
  }

  if (slot == 0) {
    float inv = (l_run > 0.f) ? (1.f / l_run) : 0.f;
    h4v ov;
#pragma unroll
    for (int c = 0; c < 4; ++c) {
      float o = acc[c] * inv + bl[c];
      if (DO_ELU) o = (o > 0.f) ? o : (__expf(o) - 1.f);
      ov[c] = (_Float16)o;
    }
    __builtin_nontemporal_store(ov, (h4v*)(hout + (size_t)node * 32 + ch0));
  }
}

// ---------------------------------------------------------------------------
// Global mean-pool (fp16 input) + 2-layer MLP.
// ---------------------------------------------------------------------------
__device__ inline int lowerb(const int* a, int n, int v) {
  int lo = 0, hi = n;
  while (lo < hi) {
    int mid = (lo + hi) >> 1;
    if (a[mid] < v) lo = mid + 1; else hi = mid;
  }
  return lo;
}

__global__ __launch_bounds__(64) void k_pool_mlp(
    const _Float16* __restrict__ h3, const int* __restrict__ batch,
    const float* __restrict__ Wm1, const float* __restrict__ bm1,
    const float* __restrict__ Wm2, const float* __restrict__ bm2,
    float* __restrict__ out, int n_nodes) {
  int g = blockIdx.x;
  int t = threadIdx.x;
  int lo = lowerb(batch, n_nodes, g);
  int hi = lowerb(batch, n_nodes, g + 1);
  int c = t & 31, half = t >> 5;
  float sum = 0.f;
  for (int i = lo + half; i < hi; i += 2) sum += (float)h3[(size_t)i * 32 + c];
  sum += __shfl_xor(sum, 32, 64);
  float cnt = (float)(hi - lo);
  float emb = sum / fmaxf(cnt, 1.f);
  __shared__ float sh_emb[32];
  __shared__ float sh_hid[64];
  if (half == 0) sh_emb[c] = emb;
  __syncthreads();
  float hv = bm1[t];
  for (int k = 0; k < 32; ++k) hv += sh_emb[k] * Wm1[k * 64 + t];
  hv = fmaxf(hv, 0.f);
  sh_hid[t] = hv;
  __syncthreads();
  float ov = bm2[t];
  for (int k = 0; k < 64; ++k) ov += sh_hid[k] * Wm2[k * 64 + t];
  out[(size_t)g * 64 + t] = ov;
}

// ---------------------------------------------------------------------------
extern "C" void kernel_launch(void* const* d_in, const int* in_sizes, int n_in,
                              void* d_out, int out_size, void* d_ws, size_t ws_size,
                              hipStream_t stream) {
  const float* x = (const float*)d_in[0];
  const int* esrc = (const int*)d_in[1];
  const int* edst = (const int*)d_in[2];
  const float* eattr = (const float*)d_in[3];
  const int* batch = (const int*)d_in[4];
  const float* W1s = (const float*)d_in[5];
  const float* W1d = (const float*)d_in[6];
  const float* W1e = (const float*)d_in[7];
  const float* b1s = (const float*)d_in[8];
  const float* b1d = (const float*)d_in[9];
  const float* att1 = (const float*)d_in[10];
  const float* bias1 = (const float*)d_in[11];
  const float* W2s = (const float*)d_in[12];
  const float* W2d = (const float*)d_in[13];
  const float* W2e = (const float*)d_in[14];
  const float* b2s = (const float*)d_in[15];
  const float* b2d = (const float*)d_in[16];
  const float* att2 = (const float*)d_in[17];
  const float* bias2 = (const float*)d_in[18];
  const float* W3s = (const float*)d_in[19];
  const float* W3d = (const float*)d_in[20];
  const float* W3e = (const float*)d_in[21];
  const float* b3s = (const float*)d_in[22];
  const float* b3d = (const float*)d_in[23];
  const float* att3 = (const float*)d_in[24];
  const float* bias3 = (const float*)d_in[25];
  const float* Wm1 = (const float*)d_in[26];
  const float* bm1 = (const float*)d_in[27];
  const float* Wm2 = (const float*)d_in[28];
  const float* bm2 = (const float*)d_in[29];

  constexpr int kNB = (kN + 255) / 256;

  char* p = (char*)d_ws;
  auto take = [&](size_t bytes) {
    char* r = p;
    p += (bytes + 255) & ~(size_t)255;
    return r;
  };
  int* row_ptr = (int*)take((size_t)(kN + 1) * sizeof(int));
  int* counts = (int*)take((size_t)kN * sizeof(int));
  int* pos = (int*)take((size_t)kE * sizeof(int));
  int* excl = (int*)take((size_t)kN * sizeof(int));
  int* bsums = (int*)take((size_t)kNB * sizeof(int));
  uint16_t* csr_src = (uint16_t*)take((size_t)kE * sizeof(uint16_t));
  _Float16* csr_ea = (_Float16*)take((size_t)kE * 8 * sizeof(_Float16));
  _Float16* xf = (_Float16*)take((size_t)kN * 32 * sizeof(_Float16));
  _Float16* Wt1 = (_Float16*)take((size_t)256 * 32 * sizeof(_Float16));
  _Float16* Wt2 = (_Float16*)take((size_t)256 * 128 * sizeof(_Float16));
  _Float16* Wt3 = (_Float16*)take((size_t)64 * 128 * sizeof(_Float16));
  _Float16* We1t = (_Float16*)take((size_t)128 * 8 * sizeof(_Float16));
  _Float16* We2t = (_Float16*)take((size_t)128 * 8 * sizeof(_Float16));
  _Float16* We3t = (_Float16*)take((size_t)32 * 8 * sizeof(_Float16));
  _Float16* xs_h = (_Float16*)take((size_t)kN * 128 * sizeof(_Float16));
  _Float16* xd_h = (_Float16*)take((size_t)kN * 128 * sizeof(_Float16));
  _Float16* hA = (_Float16*)take((size_t)kN * 128 * sizeof(_Float16));
  _Float16* hB = (_Float16*)take((size_t)kN * 128 * sizeof(_Float16));
  _Float16* h3 = (_Float16*)take((size_t)kN * 32 * sizeof(_Float16));

  // Prep first (also zeroes counts) -> CSR build -> layers.
  {
    int prep_total = kN + kN * 32 + 256 * 32 + 256 * 128 + 64 * 128 +
                     128 * 8 + 128 * 8 + 32 * 8;
    k_prep<<<(prep_total + 255) / 256, 256, 0, stream>>>(
        x, W1s, W1d, W2s, W2d, W3s, W3d, W1e, W2e, W3e,
        counts, xf, Wt1, Wt2, Wt3, We1t, We2t, We3t, kN);
  }
  k_hist<<<(kE + 255) / 256, 256, 0, stream>>>(edst, counts, pos, kE);
  k_scan_blk<<<kNB, 256, 0, stream>>>(counts, excl, bsums, kN);
  k_scan_add<<<(kN + 1 + 255) / 256, 256, 0, stream>>>(excl, bsums, row_ptr, kN, kNB);
  k_scatter<<<(kE + 255) / 256, 256, 0, stream>>>(esrc, edst, eattr, row_ptr, pos,
                                                  csr_src, csr_ea, kE);

  constexpr int kTB = (kN + 63) / 64;   // transform blocks (64 nodes each)

  // Layer 1: in=16(pad 32) -> D=128, ELU
  k_tmfma<1, 16><<<kTB, 256, 0, stream>>>(xf, Wt1, b1s, b1d, xs_h, xd_h, kN);
  k_gat128<true><<<kN, 64, 0, stream>>>(row_ptr, csr_src, csr_ea, xs_h, xd_h,
                                        att1, bias1, We1t, hA, kN);
  // Layer 2: in=128 -> D=128, ELU
  k_tmfma<4, 16><<<kTB, 256, 0, stream>>>(hA, Wt2, b2s, b2d, xs_h, xd_h, kN);
  k_gat128<true><<<kN, 64, 0, stream>>>(row_ptr, csr_src, csr_ea, xs_h, xd_h,
                                        att2, bias2, We2t, hB, kN);
  // Layer 3: in=128 -> D=32, no ELU
  k_tmfma<4, 4><<<kTB, 256, 0, stream>>>(hB, Wt3, b3s, b3d, xs_h, xd_h, kN);
  k_gat32<false><<<kN, 64, 0, stream>>>(row_ptr, csr_src, csr_ea, xs_h, xd_h,
                                        att3, bias3, We3t, h3, kN);
  // Pool + MLP
  k_pool_mlp<<<kG, 64, 0, stream>>>(h3, batch, Wm1, bm1, Wm2, bm2, (float*)d_out, kN);
}

// Round 16
// 433.147 us; speedup vs baseline: 1.0394x; 1.0394x over previous
//
#include <hip/hip_runtime.h>
#include <cstdint>
#include <cstddef>

// Problem constants (fixed by the reference).
constexpr int kN = 50000;      // nodes  (< 65536 -> src ids fit in uint16)
constexpr int kE = 800000;     // edges
constexpr int kG = 512;        // graphs
constexpr float kNegSlope = 0.2f;

typedef float f4v __attribute__((ext_vector_type(4)));
typedef _Float16 h2v __attribute__((ext_vector_type(2)));
typedef _Float16 h4v __attribute__((ext_vector_type(4)));
typedef _Float16 h8v __attribute__((ext_vector_type(8)));

#if defined(__has_builtin)
#if __has_builtin(__builtin_amdgcn_fdot2)
#define HAS_FDOT2 1
#endif
#endif

__device__ inline float dot2f(h2v a, h2v b, float c) {
#ifdef HAS_FDOT2
  return __builtin_amdgcn_fdot2(a, b, c, false);
#else
  return c + (float)a.x * (float)b.x + (float)a.y * (float)b.y;
#endif
}

// ---------------------------------------------------------------------------
// CSR build: histogram of dst (records each edge's within-node slot) ->
// block-scan -> fused top-scan+add -> scatter (no atomics in scatter).
// ---------------------------------------------------------------------------
__global__ void k_hist(const int* __restrict__ dst, int* __restrict__ counts,
                       int* __restrict__ pos, int n) {
  int i = blockIdx.x * blockDim.x + threadIdx.x;
  if (i < n) pos[i] = atomicAdd(&counts[dst[i]], 1);
}

__global__ __launch_bounds__(256) void k_scan_blk(const int* __restrict__ counts,
                                                  int* __restrict__ excl,
                                                  int* __restrict__ bsums, int n) {
  __shared__ int sh[256];
  int tid = threadIdx.x;
  int i = blockIdx.x * 256 + tid;
  int c = (i < n) ? counts[i] : 0;
  sh[tid] = c;
  __syncthreads();
  for (int off = 1; off < 256; off <<= 1) {
    int t = (tid >= off) ? sh[tid - off] : 0;
    __syncthreads();
    sh[tid] += t;
    __syncthreads();
  }
  if (i < n) excl[i] = sh[tid] - c;
  if (tid == 255) bsums[blockIdx.x] = sh[255];
}

// Fused top-scan + add: every block scans the (<=256) block sums in LDS,
// picks its own offset, and emits final row_ptr (incl. row_ptr[n] = total).
__global__ __launch_bounds__(256) void k_scan_add(const int* __restrict__ excl,
                                                  const int* __restrict__ bsums,
                                                  int* __restrict__ row_ptr,
                                                  int n, int nb) {
  __shared__ int sh[256];
  int tid = threadIdx.x;
  int c = (tid < nb) ? bsums[tid] : 0;
  sh[tid] = c;
  __syncthreads();
  for (int off = 1; off < 256; off <<= 1) {
    int t = (tid >= off) ? sh[tid - off] : 0;
    __syncthreads();
    sh[tid] += t;
    __syncthreads();
  }
  int top = (blockIdx.x > 0) ? sh[blockIdx.x - 1] : 0;
  int total = sh[nb - 1];
  __syncthreads();
  int i = blockIdx.x * 256 + tid;
  if (i < n) row_ptr[i] = excl[i] + top;
  if (i == n) row_ptr[n] = total;
}

__global__ void k_scatter(const int* __restrict__ src, const int* __restrict__ dst,
                          const float* __restrict__ eattr,
                          const int* __restrict__ row_ptr, const int* __restrict__ pos,
                          uint16_t* __restrict__ csr_src, _Float16* __restrict__ csr_ea,
                          int n) {
  int i = blockIdx.x * blockDim.x + threadIdx.x;
  if (i >= n) return;
  int p = row_ptr[dst[i]] + pos[i];
  csr_src[p] = (uint16_t)src[i];
  const float4* s4 = (const float4*)eattr + (size_t)i * 2;
  float4 a = s4[0];
  float4 b = s4[1];
  h8v hv;
  hv[0] = (_Float16)a.x; hv[1] = (_Float16)a.y; hv[2] = (_Float16)a.z; hv[3] = (_Float16)a.w;
  hv[4] = (_Float16)b.x; hv[5] = (_Float16)b.y; hv[6] = (_Float16)b.z; hv[7] = (_Float16)b.w;
  *(h8v*)(csr_ea + (size_t)p * 8) = hv;
}

// ---------------------------------------------------------------------------
// Fused prep: ALSO zeroes counts (replaces the memset launch; prep runs
// before k_hist).  x -> fp16 padded K=32; weight pairs -> fp16 transposed
// Wt buffers; We -> fp16 transposed Wet[ch][k] tables.
// ---------------------------------------------------------------------------
__global__ __launch_bounds__(256) void k_prep(
    const float* __restrict__ x,
    const float* __restrict__ W1s, const float* __restrict__ W1d,
    const float* __restrict__ W2s, const float* __restrict__ W2d,
    const float* __restrict__ W3s, const float* __restrict__ W3d,
    const float* __restrict__ W1e, const float* __restrict__ W2e,
    const float* __restrict__ W3e,
    int* __restrict__ counts,
    _Float16* __restrict__ xf, _Float16* __restrict__ Wt1,
    _Float16* __restrict__ Wt2, _Float16* __restrict__ Wt3,
    _Float16* __restrict__ We1t, _Float16* __restrict__ We2t,
    _Float16* __restrict__ We3t, int n) {
  int i = blockIdx.x * 256 + threadIdx.x;
  if (i < n) {
    counts[i] = 0;
  }
  i -= n;
  if (i < 0) return;
  int r0 = n * 32;
  if (i < r0) {
    int node = i >> 5, col = i & 31;
    xf[i] = (col < 16) ? (_Float16)x[node * 16 + col] : (_Float16)0.f;
    return;
  }
  i -= r0;
  if (i < 256 * 32) {  // Wt1: 256 cols x K=32, IND=16, OUTD=128
    int c = i >> 5, k = i & 31;
    const float* W = (c < 128) ? W1s : W1d;
    Wt1[i] = (k < 16) ? (_Float16)W[k * 128 + (c & 127)] : (_Float16)0.f;
    return;
  }
  i -= 256 * 32;
  if (i < 256 * 128) {  // Wt2: 256 x 128, IND=128, OUTD=128
    int c = i >> 7, k = i & 127;
    const float* W = (c < 128) ? W2s : W2d;
    Wt2[i] = (_Float16)W[k * 128 + (c & 127)];
    return;
  }
  i -= 256 * 128;
  if (i < 64 * 128) {  // Wt3: 64 x 128, IND=128, OUTD=32
    int c = i >> 7, k = i & 127;
    const float* W = (c < 32) ? W3s : W3d;
    int cc = (c < 32) ? c : c - 32;
    Wt3[i] = (_Float16)W[k * 32 + cc];
    return;
  }
  i -= 64 * 128;
  if (i < 128 * 8) {  // We1t[ch][k] = W1e[k][ch]
    We1t[i] = (_Float16)W1e[(i & 7) * 128 + (i >> 3)];
    return;
  }
  i -= 128 * 8;
  if (i < 128 * 8) {  // We2t
    We2t[i] = (_Float16)W2e[(i & 7) * 128 + (i >> 3)];
    return;
  }
  i -= 128 * 8;
  if (i < 32 * 8) {   // We3t
    We3t[i] = (_Float16)W3e[(i & 7) * 32 + (i >> 3)];
  }
}

// ---------------------------------------------------------------------------
// MFMA node transform: [xs | xd] = h @ [Ws | Wd] + [bs | bd].  Both outputs
// fp16 (xd quantization adds ~2e-4 to final error; margin 4x).
// ---------------------------------------------------------------------------
template <int KT, int NC2>
__global__ __launch_bounds__(256) void k_tmfma(
    const _Float16* __restrict__ hf, const _Float16* __restrict__ Wt,
    const float* __restrict__ bs, const float* __restrict__ bd,
    _Float16* __restrict__ xs_h, _Float16* __restrict__ xd_h, int n_nodes) {
  constexpr int K = KT * 32;
  constexpr int NCS = NC2 / 2;
  constexpr int D = NCS * 16;
  int lane = threadIdx.x & 63;
  int wid = threadIdx.x >> 6;
  int m = lane & 15;
  int quad = lane >> 4;
  int base = (blockIdx.x * 4 + wid) * 16;
  if (base >= n_nodes) return;
  int arow = min(base + m, n_nodes - 1);

  h8v a[KT];
#pragma unroll
  for (int t = 0; t < KT; ++t)
    a[t] = *(const h8v*)(hf + (size_t)arow * K + t * 32 + quad * 8);

  bool full = (base + 16 <= n_nodes);
#pragma unroll
  for (int c = 0; c < NC2; ++c) {
    f4v acc = {0.f, 0.f, 0.f, 0.f};
#pragma unroll
    for (int t = 0; t < KT; ++t) {
      h8v b = *(const h8v*)(Wt + (size_t)(c * 16 + m) * K + t * 32 + quad * 8);
      acc = __builtin_amdgcn_mfma_f32_16x16x32_f16(a[t], b, acc, 0, 0, 0);
    }
    float bv = (c < NCS) ? bs[c * 16 + m] : bd[(c - NCS) * 16 + m];
#pragma unroll
    for (int r = 0; r < 4; ++r) {
      int node = base + quad * 4 + r;
      if (full || node < n_nodes) {
        if (c < NCS)
          xs_h[(size_t)node * D + c * 16 + m] = (_Float16)(acc[r] + bv);
        else
          xd_h[(size_t)node * D + (c - NCS) * 16 + m] = (_Float16)(acc[r] + bv);
      }
    }
  }
}

// ---------------------------------------------------------------------------
// Fused GATv2, D=128 (H=4, C=32): NON-persistent, ONE WAVE PER BLOCK
// (64 threads — waves retire individually; measured optimum of the block-
// granularity curve 51%->54%->63%).  TWO edge slots (32 lanes/slot,
// 4 ch/lane — measured knee).  Pipeline depth 2 (R12/R15: depth 4 costs
// +8..12 VGPR -> occupancy cliff, regressed both guarded and unguarded)
// with WAVE-UNIFORM prefetch guard — no extra registers, kills the ~2
// wasted wrapped prefetches per node (R14 FETCH 93.6 vs R11 88.6 MB).
// No-max softmax (scores bounded ~|6| << 88).  Chunked: 64 src ids
// preloaded coalesced (lanes>=cnt hold 0 -> valid address, masked by p=0),
// ea staged in wave-private LDS, dot2 chain seeded with xs+xd.
// ---------------------------------------------------------------------------
template <bool DO_ELU>
__global__ __launch_bounds__(64) void k_gat128(
    const int* __restrict__ row_ptr, const uint16_t* __restrict__ csr_src,
    const _Float16* __restrict__ csr_ea,
    const _Float16* __restrict__ xs_h, const _Float16* __restrict__ xd_h,
    const float* __restrict__ att, const float* __restrict__ bias,
    const _Float16* __restrict__ Wet, _Float16* __restrict__ hout, int n_nodes) {
  __shared__ _Float16 sea[64 * 8];
  int lane = threadIdx.x & 63;
  int node = blockIdx.x;
  if (node >= n_nodes) return;
  int slot = lane >> 5;   // 0 / 1
  int sl = lane & 31;
  int ch0 = sl * 4;       // this lane's 4 channels; head = sl>>3

  float4 at4 = *(const float4*)(att + ch0);
  float atl[4] = {at4.x, at4.y, at4.z, at4.w};
  h2v we[4][4];
#pragma unroll
  for (int c = 0; c < 4; ++c) {
    h8v wv = *(const h8v*)(Wet + (size_t)(ch0 + c) * 8);
#pragma unroll
    for (int t = 0; t < 4; ++t) {
      h2v w;
      w[0] = wv[2 * t];
      w[1] = wv[2 * t + 1];
      we[c][t] = w;
    }
  }
  float4 bv4 = *(const float4*)(bias + ch0);
  float bl[4] = {bv4.x, bv4.y, bv4.z, bv4.w};

  h4v xdh = *(const h4v*)(xd_h + (size_t)node * 128 + ch0);
  float xdl[4];
#pragma unroll
  for (int c = 0; c < 4; ++c) xdl[c] = (float)xdh[c];

  const char* xsb = (const char*)xs_h;
  uint32_t chb = (uint32_t)sl * 8u;  // byte offset of this lane's 4 fp16 ch

  float acc[4] = {0.f, 0.f, 0.f, 0.f};
  float l_run = 0.f;
  int beg = row_ptr[node], end = row_ptr[node + 1];

  for (int cbeg = beg; cbeg < end; cbeg += 64) {
    int cnt = min(end - cbeg, 64);
    int sv = (lane < cnt) ? (int)__builtin_nontemporal_load(csr_src + cbeg + lane) : 0;
    if (lane < cnt) {
      h8v t = __builtin_nontemporal_load((const h8v*)(csr_ea + (size_t)(cbeg + lane) * 8));
      *(h8v*)&sea[lane * 8] = t;
    }

    auto addr = [&](int i) -> uint32_t {
      int s = __shfl(sv, i + slot, 64);  // idx <= 63 everywhere it's used
      return (uint32_t)s * 256u + chb;
    };
    auto consume = [&](int i, h4v xh) {
      int e = i + slot;                  // <= 63 by construction
      const h2v* pe = (const h2v*)&sea[e * 8];
      h2v a0 = pe[0], a1 = pe[1], a2 = pe[2], a3 = pe[3];
      float xf[4];
#pragma unroll
      for (int c = 0; c < 4; ++c) xf[c] = (float)xh[c];
      float sc = 0.f;
#pragma unroll
      for (int c = 0; c < 4; ++c) {
        float z = dot2f(a3, we[c][3],
                  dot2f(a2, we[c][2],
                  dot2f(a1, we[c][1],
                  dot2f(a0, we[c][0], xf[c] + xdl[c]))));
        z = fmaxf(z, kNegSlope * z);
        sc = fmaf(z, atl[c], sc);
      }
      // head score: reduce over the 8 lanes covering this head's 32 ch
      sc += __shfl_xor(sc, 1, 64);
      sc += __shfl_xor(sc, 2, 64);
      sc += __shfl_xor(sc, 4, 64);
      float p = (e < cnt) ? __expf(sc) : 0.f;
      l_run += p;
#pragma unroll
      for (int c = 0; c < 4; ++c) acc[c] += p * xf[c];
    };

    uint32_t oa = addr(0), ob = addr(2);
    h4v xa = *(const h4v*)(xsb + oa);
    h4v xb = *(const h4v*)(xsb + ob);
    for (int i = 0; i < cnt; i += 4) {
      bool pf = (i + 4 < cnt);           // wave-uniform: zero wasted gathers
      h4v pa, pb;
      if (pf) {
        uint32_t na = addr(i + 4), nb = addr(i + 6);
        pa = *(const h4v*)(xsb + na);
        pb = *(const h4v*)(xsb + nb);
      }
      consume(i, xa);
      consume(i + 2, xb);
      if (pf) { xa = pa; xb = pb; }
    }
  }

  // combine the two slots
  l_run += __shfl_xor(l_run, 32, 64);
#pragma unroll
  for (int c = 0; c < 4; ++c) acc[c] += __shfl_xor(acc[c], 32, 64);

  if (slot == 0) {
    float inv = (l_run > 0.f) ? (1.f / l_run) : 0.f;
    h4v ov;
#pragma unroll
    for (int c = 0; c < 4; ++c) {
      float o = acc[c] * inv + bl[c];
      if (DO_ELU) o = (o > 0.f) ? o : (__expf(o) - 1.f);
      ov[c] = (_Float16)o;
    }
    __builtin_nontemporal_store(ov, (h4v*)(hout + (size_t)node * 128 + ch0));
  }
}

// ---------------------------------------------------------------------------
// Fused GATv2, D=32 (H=1, C=32): NON-persistent, one wave per block,
// EIGHT edge slots (8 lanes/slot, 4 ch/lane), pipeline depth 2 with
// wave-uniform prefetch guard.  Chunk = 32 edges.
// ---------------------------------------------------------------------------
template <bool DO_ELU>
__global__ __launch_bounds__(64) void k_gat32(
    const int* __restrict__ row_ptr, const uint16_t* __restrict__ csr_src,
    const _Float16* __restrict__ csr_ea,
    const _Float16* __restrict__ xs_h, const _Float16* __restrict__ xd_h,
    const float* __restrict__ att, const float* __restrict__ bias,
    const _Float16* __restrict__ Wet, _Float16* __restrict__ hout, int n_nodes) {
  __shared__ _Float16 sea[32 * 8];
  int lane = threadIdx.x & 63;
  int node = blockIdx.x;
  if (node >= n_nodes) return;
  int slot = lane >> 3;   // 0..7
  int sl = lane & 7;
  int ch0 = sl * 4;

  float4 at4 = *(const float4*)(att + ch0);
  float atl[4] = {at4.x, at4.y, at4.z, at4.w};
  h2v we[4][4];
#pragma unroll
  for (int c = 0; c < 4; ++c) {
    h8v wv = *(const h8v*)(Wet + (size_t)(ch0 + c) * 8);
#pragma unroll
    for (int t = 0; t < 4; ++t) {
      h2v w;
      w[0] = wv[2 * t];
      w[1] = wv[2 * t + 1];
      we[c][t] = w;
    }
  }
  float4 bv4 = *(const float4*)(bias + ch0);
  float bl[4] = {bv4.x, bv4.y, bv4.z, bv4.w};

  h4v xdh = *(const h4v*)(xd_h + (size_t)node * 32 + ch0);
  float xdl[4];
#pragma unroll
  for (int c = 0; c < 4; ++c) xdl[c] = (float)xdh[c];

  const char* xsb = (const char*)xs_h;
  uint32_t chb = (uint32_t)sl * 8u;

  float acc[4] = {0.f, 0.f, 0.f, 0.f};
  float l_run = 0.f;
  int beg = row_ptr[node], end = row_ptr[node + 1];

  for (int cbeg = beg; cbeg < end; cbeg += 32) {
    int cnt = min(end - cbeg, 32);
    int sv = (lane < cnt) ? (int)__builtin_nontemporal_load(csr_src + cbeg + lane) : 0;
    if (lane < cnt) {
      h8v t = __builtin_nontemporal_load((const h8v*)(csr_ea + (size_t)(cbeg + lane) * 8));
      *(h8v*)&sea[lane * 8] = t;
    }

    auto addr = [&](int i) -> uint32_t {
      int idx = (i + slot) & 31;         // wrap within this chunk's 32 ids
      int s = __shfl(sv, idx, 64);
      return (uint32_t)s * 64u + chb;
    };
    auto consume = [&](int i, h4v xh) {
      int e = i + slot;                  // <= 31 by construction
      const h2v* pe = (const h2v*)&sea[e * 8];
      h2v a0 = pe[0], a1 = pe[1], a2 = pe[2], a3 = pe[3];
      float xf[4];
#pragma unroll
      for (int c = 0; c < 4; ++c) xf[c] = (float)xh[c];
      float sc = 0.f;
#pragma unroll
      for (int c = 0; c < 4; ++c) {
        float z = dot2f(a3, we[c][3],
                  dot2f(a2, we[c][2],
                  dot2f(a1, we[c][1],
                  dot2f(a0, we[c][0], xf[c] + xdl[c]))));
        z = fmaxf(z, kNegSlope * z);
        sc = fmaf(z, atl[c], sc);
      }
      // head = 32 ch = 8 lanes (this slot)
      sc += __shfl_xor(sc, 1, 64);
      sc += __shfl_xor(sc, 2, 64);
      sc += __shfl_xor(sc, 4, 64);
      float p = (e < cnt) ? __expf(sc) : 0.f;
      l_run += p;
#pragma unroll
      for (int c = 0; c < 4; ++c) acc[c] += p * xf[c];
    };

    uint32_t oa = addr(0), ob = addr(8);
    h4v xa = *(const h4v*)(xsb + oa);
    h4v xb = *(const h4v*)(xsb + ob);
    for (int i = 0; i < cnt; i += 16) {
      bool pf = (i + 16 < cnt);          // wave-uniform guard
      h4v pa, pb;
      if (pf) {
        uint32_t na = addr(i + 16), nb = addr(i + 24);
        pa = *(const h4v*)(xsb + na);
        pb = *(const h4v*)(xsb + nb);
      }
      consume(i, xa);
      consume(i + 8, xb);
      if (pf) { xa = pa; xb = pb; }
    }
  }

  // combine the 8 slots (lanes with equal sl)
#pragma unroll
  for (int off = 8; off < 64; off <<= 1) {
    l_run += __shfl_xor(l_run, off, 64);
#pragma unroll
    for (int c = 0; c < 4; ++c) acc[c] += __shfl_xor(acc[c], off, 64);
  }

  if (slot == 0) {
    float inv = (l_run > 0.f) ? (1.f / l_run) : 0.f;
    h4v ov;
#pragma unroll
    for (int c = 0; c < 4; ++c) {
      float o = acc[c] * inv + bl[c];
      if (DO_ELU) o = (o > 0.f) ? o : (__expf(o) - 1.f);
      ov[c] = (_Float16)o;
    }
    __builtin_nontemporal_store(ov, (h4v*)(hout + (size_t)node * 32 + ch0));
  }
}

// ---------------------------------------------------------------------------
// Global mean-pool (fp16 input) + 2-layer MLP.
// ---------------------------------------------------------------------------
__device__ inline int lowerb(const int* a, int n, int v) {
  int lo = 0, hi = n;
  while (lo < hi) {
    int mid = (lo + hi) >> 1;
    if (a[mid] < v) lo = mid + 1; else hi = mid;
  }
  return lo;
}

__global__ __launch_bounds__(64) void k_pool_mlp(
    const _Float16* __restrict__ h3, const int* __restrict__ batch,
    const float* __restrict__ Wm1, const float* __restrict__ bm1,
    const float* __restrict__ Wm2, const float* __restrict__ bm2,
    float* __restrict__ out, int n_nodes) {
  int g = blockIdx.x;
  int t = threadIdx.x;
  int lo = lowerb(batch, n_nodes, g);
  int hi = lowerb(batch, n_nodes, g + 1);
  int c = t & 31, half = t >> 5;
  float sum = 0.f;
  for (int i = lo + half; i < hi; i += 2) sum += (float)h3[(size_t)i * 32 + c];
  sum += __shfl_xor(sum, 32, 64);
  float cnt = (float)(hi - lo);
  float emb = sum / fmaxf(cnt, 1.f);
  __shared__ float sh_emb[32];
  __shared__ float sh_hid[64];
  if (half == 0) sh_emb[c] = emb;
  __syncthreads();
  float hv = bm1[t];
  for (int k = 0; k < 32; ++k) hv += sh_emb[k] * Wm1[k * 64 + t];
  hv = fmaxf(hv, 0.f);
  sh_hid[t] = hv;
  __syncthreads();
  float ov = bm2[t];
  for (int k = 0; k < 64; ++k) ov += sh_hid[k] * Wm2[k * 64 + t];
  out[(size_t)g * 64 + t] = ov;
}

// ---------------------------------------------------------------------------
extern "C" void kernel_launch(void* const* d_in, const int* in_sizes, int n_in,
                              void* d_out, int out_size, void* d_ws, size_t ws_size,
                              hipStream_t stream) {
  const float* x = (const float*)d_in[0];
  const int* esrc = (const int*)d_in[1];
  const int* edst = (const int*)d_in[2];
  const float* eattr = (const float*)d_in[3];
  const int* batch = (const int*)d_in[4];
  const float* W1s = (const float*)d_in[5];
  const float* W1d = (const float*)d_in[6];
  const float* W1e = (const float*)d_in[7];
  const float* b1s = (const float*)d_in[8];
  const float* b1d = (const float*)d_in[9];
  const float* att1 = (const float*)d_in[10];
  const float* bias1 = (const float*)d_in[11];
  const float* W2s = (const float*)d_in[12];
  const float* W2d = (const float*)d_in[13];
  const float* W2e = (const float*)d_in[14];
  const float* b2s = (const float*)d_in[15];
  const float* b2d = (const float*)d_in[16];
  const float* att2 = (const float*)d_in[17];
  const float* bias2 = (const float*)d_in[18];
  const float* W3s = (const float*)d_in[19];
  const float* W3d = (const float*)d_in[20];
  const float* W3e = (const float*)d_in[21];
  const float* b3s = (const float*)d_in[22];
  const float* b3d = (const float*)d_in[23];
  const float* att3 = (const float*)d_in[24];
  const float* bias3 = (const float*)d_in[25];
  const float* Wm1 = (const float*)d_in[26];
  const float* bm1 = (const float*)d_in[27];
  const float* Wm2 = (const float*)d_in[28];
  const float* bm2 = (const float*)d_in[29];

  constexpr int kNB = (kN + 255) / 256;

  char* p = (char*)d_ws;
  auto take = [&](size_t bytes) {
    char* r = p;
    p += (bytes + 255) & ~(size_t)255;
    return r;
  };
  int* row_ptr = (int*)take((size_t)(kN + 1) * sizeof(int));
  int* counts = (int*)take((size_t)kN * sizeof(int));
  int* pos = (int*)take((size_t)kE * sizeof(int));
  int* excl = (int*)take((size_t)kN * sizeof(int));
  int* bsums = (int*)take((size_t)kNB * sizeof(int));
  uint16_t* csr_src = (uint16_t*)take((size_t)kE * sizeof(uint16_t));
  _Float16* csr_ea = (_Float16*)take((size_t)kE * 8 * sizeof(_Float16));
  _Float16* xf = (_Float16*)take((size_t)kN * 32 * sizeof(_Float16));
  _Float16* Wt1 = (_Float16*)take((size_t)256 * 32 * sizeof(_Float16));
  _Float16* Wt2 = (_Float16*)take((size_t)256 * 128 * sizeof(_Float16));
  _Float16* Wt3 = (_Float16*)take((size_t)64 * 128 * sizeof(_Float16));
  _Float16* We1t = (_Float16*)take((size_t)128 * 8 * sizeof(_Float16));
  _Float16* We2t = (_Float16*)take((size_t)128 * 8 * sizeof(_Float16));
  _Float16* We3t = (_Float16*)take((size_t)32 * 8 * sizeof(_Float16));
  _Float16* xs_h = (_Float16*)take((size_t)kN * 128 * sizeof(_Float16));
  _Float16* xd_h = (_Float16*)take((size_t)kN * 128 * sizeof(_Float16));
  _Float16* hA = (_Float16*)take((size_t)kN * 128 * sizeof(_Float16));
  _Float16* hB = (_Float16*)take((size_t)kN * 128 * sizeof(_Float16));
  _Float16* h3 = (_Float16*)take((size_t)kN * 32 * sizeof(_Float16));

  // Prep first (also zeroes counts) -> CSR build -> layers.
  {
    int prep_total = kN + kN * 32 + 256 * 32 + 256 * 128 + 64 * 128 +
                     128 * 8 + 128 * 8 + 32 * 8;
    k_prep<<<(prep_total + 255) / 256, 256, 0, stream>>>(
        x, W1s, W1d, W2s, W2d, W3s, W3d, W1e, W2e, W3e,
        counts, xf, Wt1, Wt2, Wt3, We1t, We2t, We3t, kN);
  }
  k_hist<<<(kE + 255) / 256, 256, 0, stream>>>(edst, counts, pos, kE);
  k_scan_blk<<<kNB, 256, 0, stream>>>(counts, excl, bsums, kN);
  k_scan_add<<<(kN + 1 + 255) / 256, 256, 0, stream>>>(excl, bsums, row_ptr, kN, kNB);
  k_scatter<<<(kE + 255) / 256, 256, 0, stream>>>(esrc, edst, eattr, row_ptr, pos,
                                                  csr_src, csr_ea, kE);

  constexpr int kTB = (kN + 63) / 64;   // transform blocks (64 nodes each)

  // Layer 1: in=16(pad 32) -> D=128, ELU
  k_tmfma<1, 16><<<kTB, 256, 0, stream>>>(xf, Wt1, b1s, b1d, xs_h, xd_h, kN);
  k_gat128<true><<<kN, 64, 0, stream>>>(row_ptr, csr_src, csr_ea, xs_h, xd_h,
                                        att1, bias1, We1t, hA, kN);
  // Layer 2: in=128 -> D=128, ELU
  k_tmfma<4, 16><<<kTB, 256, 0, stream>>>(hA, Wt2, b2s, b2d, xs_h, xd_h, kN);
  k_gat128<true><<<kN, 64, 0, stream>>>(row_ptr, csr_src, csr_ea, xs_h, xd_h,
                                        att2, bias2, We2t, hB, kN);
  // Layer 3: in=128 -> D=32, no ELU
  k_tmfma<4, 4><<<kTB, 256, 0, stream>>>(hB, Wt3, b3s, b3d, xs_h, xd_h, kN);
  k_gat32<false><<<kN, 64, 0, stream>>>(row_ptr, csr_src, csr_ea, xs_h, xd_h,
                                        att3, bias3, We3t, h3, kN);
  // Pool + MLP
  k_pool_mlp<<<kG, 64, 0, stream>>>(h3, batch, Wm1, bm1, Wm2, bm2, (float*)d_out, kN);
}